// Round 11
// baseline (140.491 us; speedup 1.0000x reference)
//
#include <hip/hip_runtime.h>

#define NB 4
#define NH 16
#define NN 4096
#define HS 64
#define NA 64
#define DM 1024
#define NBH (NB*NH)
#define SCALE 0.125f

typedef __attribute__((ext_vector_type(8))) short bf16x8;
typedef __attribute__((ext_vector_type(4))) float f32x4;

__device__ __forceinline__ unsigned short f2bf(float f) {
  unsigned u = __float_as_uint(f);
  u += 0x7FFF + ((u >> 16) & 1);  // RNE
  return (unsigned short)(u >> 16);
}

// non-temporal read-once stream load (hint-only; same bytes as plain load)
__device__ __forceinline__ f32x4 ntload4(const float* p) {
  return __builtin_nontemporal_load((const f32x4*)p);
}

__device__ __forceinline__ void gload_lds16(const void* g, void* l) {
  __builtin_amdgcn_global_load_lds(
      (const __attribute__((address_space(1))) unsigned int*)g,
      (__attribute__((address_space(3))) unsigned int*)l, 16, 0, 0);
}

__device__ __forceinline__ void dot44(float (&c)[4][4], const float4 (&a)[4], const float4 (&b)[4]) {
#pragma unroll
  for (int i = 0; i < 4; ++i)
#pragma unroll
    for (int j = 0; j < 4; ++j) {
      c[i][j] = fmaf(a[i].x, b[j].x, c[i][j]);
      c[i][j] = fmaf(a[i].y, b[j].y, c[i][j]);
      c[i][j] = fmaf(a[i].z, b[j].z, c[i][j]);
      c[i][j] = fmaf(a[i].w, b[j].w, c[i][j]);
    }
}

// K0: foldq[h][a][d] = ((agents[h]@Wq^T + bq) @ Wk) * SCALE, as bf16.
__global__ __launch_bounds__(256) void k0_fold(
    const float* __restrict__ agents, const float* __restrict__ Wq,
    const float* __restrict__ bq, const float* __restrict__ Wk,
    unsigned short* __restrict__ foldqbf) {
  const int h = blockIdx.x, tid = threadIdx.x;
  const int tn = tid & 15, tm = tid >> 4;
  __shared__ float AG[64][68];   // agents [a][d]
  __shared__ float WB[64][68];   // Wq [e][d]
  __shared__ float QA[64][68];   // q_agents [a][e]
  __shared__ float WKT[64][68];  // Wk^T [d][e]
  for (int i = tid; i < 1024; i += 256) {
    const int r = i >> 4, c4 = (i & 15) * 4;
    *(float4*)&AG[r][c4] = *(const float4*)(agents + h * 4096 + r * 64 + c4);
    *(float4*)&WB[r][c4] = *(const float4*)(Wq + r * 64 + c4);
    const float4 f = *(const float4*)(Wk + r * 64 + c4);  // Wk[e=r][d4..]
    WKT[c4 + 0][r] = f.x; WKT[c4 + 1][r] = f.y;
    WKT[c4 + 2][r] = f.z; WKT[c4 + 3][r] = f.w;
  }
  __syncthreads();
  {
    const float4 bb = *(const float4*)(bq + tn * 4);
    float acc[4][4];
#pragma unroll
    for (int i = 0; i < 4; ++i) {
      acc[i][0] = bb.x; acc[i][1] = bb.y; acc[i][2] = bb.z; acc[i][3] = bb.w;
    }
    for (int d4 = 0; d4 < 64; d4 += 4) {
      float4 a4[4], b4[4];
#pragma unroll
      for (int i = 0; i < 4; ++i) a4[i] = *(const float4*)&AG[tm * 4 + i][d4];
#pragma unroll
      for (int j = 0; j < 4; ++j) b4[j] = *(const float4*)&WB[tn * 4 + j][d4];
      dot44(acc, a4, b4);
    }
#pragma unroll
    for (int i = 0; i < 4; ++i)
      *(float4*)&QA[tm * 4 + i][tn * 4] =
          make_float4(acc[i][0], acc[i][1], acc[i][2], acc[i][3]);
  }
  __syncthreads();
  {
    float acc[4][4] = {};
    for (int e4 = 0; e4 < 64; e4 += 4) {
      float4 a4[4], b4[4];
#pragma unroll
      for (int i = 0; i < 4; ++i) a4[i] = *(const float4*)&QA[tm * 4 + i][e4];
#pragma unroll
      for (int j = 0; j < 4; ++j) b4[j] = *(const float4*)&WKT[tn * 4 + j][e4];
      dot44(acc, a4, b4);
    }
#pragma unroll
    for (int i = 0; i < 4; ++i) {
      ushort4 o;
      o.x = f2bf(acc[i][0] * SCALE); o.y = f2bf(acc[i][1] * SCALE);
      o.z = f2bf(acc[i][2] * SCALE); o.w = f2bf(acc[i][3] * SCALE);
      *(ushort4*)(foldqbf + h * 4096 + (tm * 4 + i) * 64 + tn * 4) = o;
    }
  }
}

// K2: stage-1 flash partials via bf16 MFMA. grid(chunk=16, bh=64), 4 waves.
// R7: a-partitioned QK -> ES wave-private, 2 barriers/tile.
// R11: k/v loads NONTEMPORAL (134 MB read-once stream; don't evict pctx).
__global__ __launch_bounds__(256) void k2_mfma(
    const float* __restrict__ kraw, const float* __restrict__ vraw,
    const unsigned short* __restrict__ foldqbf,
    float* __restrict__ pctx, float* __restrict__ psum) {
  __shared__ unsigned short FQ[64 * 72];  // foldq [a][d], scaled bf16
  __shared__ unsigned short KN[64 * 72];  // K natural [n][d]
  __shared__ unsigned short VT[64 * 72];  // V^T [d][n ^ 8*((d>>2)&7)]
  __shared__ unsigned short ES[64 * 72];  // exp scores [a][n], wave-private rows
  const int chunk = blockIdx.x, bh = blockIdx.y, h = bh & 15;
  const int tid = threadIdx.x;
  const int lane = tid & 63, w = tid >> 6;
  const int l15 = lane & 15, lg = lane >> 4;

  const size_t kvbase = ((size_t)bh * NN + chunk * 256) * HS;
  f32x4 kreg[4], vreg[4];
#pragma unroll
  for (int i0 = 0; i0 < 4; ++i0) {
    const int i = tid + i0 * 256;
    kreg[i0] = ntload4(kraw + kvbase + (size_t)i * 4);
    vreg[i0] = ntload4(vraw + kvbase + (size_t)i * 4);
  }

  for (int i = tid; i < 512; i += 256) {
    const int a = i >> 3, d8 = (i & 7) * 8;
    *(uint4*)&FQ[a * 72 + d8] = *(const uint4*)(foldqbf + h * 4096 + a * 64 + d8);
  }

  f32x4 ctx[4];
#pragma unroll
  for (int df = 0; df < 4; ++df) ctx[df] = (f32x4){0.f, 0.f, 0.f, 0.f};
  f32x4 pacc = (f32x4){0.f, 0.f, 0.f, 0.f};
  const short one_bf = (short)0x3F80;
  const bf16x8 ones = {one_bf, one_bf, one_bf, one_bf, one_bf, one_bf, one_bf, one_bf};

  for (int t = 0; t < 4; ++t) {
    __syncthreads();  // bar A: prev PV reads of KN/VT done
#pragma unroll
    for (int i0 = 0; i0 < 4; ++i0) {
      const int i = tid + i0 * 256;
      const int n = i >> 4, d4 = (i & 15) * 4;
      const f32x4 f = kreg[i0];
      const unsigned klo = f2bf(f.x) | ((unsigned)f2bf(f.y) << 16);
      const unsigned khi = f2bf(f.z) | ((unsigned)f2bf(f.w) << 16);
      *(uint2*)&KN[n * 72 + d4] = make_uint2(klo, khi);
      const f32x4 g = vreg[i0];
      const int nn = n ^ (8 * (i & 7));
      VT[(d4 + 0) * 72 + nn] = f2bf(g.x);
      VT[(d4 + 1) * 72 + nn] = f2bf(g.y);
      VT[(d4 + 2) * 72 + nn] = f2bf(g.z);
      VT[(d4 + 3) * 72 + nn] = f2bf(g.w);
    }
    if (t < 3) {
#pragma unroll
      for (int i0 = 0; i0 < 4; ++i0) {
        const int i = tid + i0 * 256;
        kreg[i0] = ntload4(kraw + kvbase + (size_t)(t + 1) * 4096 + (size_t)i * 4);
        vreg[i0] = ntload4(vraw + kvbase + (size_t)(t + 1) * 4096 + (size_t)i * 4);
      }
    }
    __syncthreads();  // bar B: KN/VT (and FQ) ready
    // ---- QK, a-partitioned: wave w owns a-cols w*16..w*16+15 ----
    const bf16x8 bq0 = *(const bf16x8*)&FQ[(w * 16 + l15) * 72 + lg * 8];
    const bf16x8 bq1 = *(const bf16x8*)&FQ[(w * 16 + l15) * 72 + 32 + lg * 8];
    f32x4 sacc[4];
#pragma unroll
    for (int nf = 0; nf < 4; ++nf) {
      sacc[nf] = (f32x4){0.f, 0.f, 0.f, 0.f};
      const bf16x8 a0 = *(const bf16x8*)&KN[(nf * 16 + l15) * 72 + lg * 8];
      const bf16x8 a1 = *(const bf16x8*)&KN[(nf * 16 + l15) * 72 + 32 + lg * 8];
      sacc[nf] = __builtin_amdgcn_mfma_f32_16x16x32_bf16(a0, bq0, sacc[nf], 0, 0, 0);
      sacc[nf] = __builtin_amdgcn_mfma_f32_16x16x32_bf16(a1, bq1, sacc[nf], 0, 0, 0);
    }
#pragma unroll
    for (int nf = 0; nf < 4; ++nf) {
      const unsigned e0 = f2bf(__expf(sacc[nf][0])) | ((unsigned)f2bf(__expf(sacc[nf][1])) << 16);
      const unsigned e1 = f2bf(__expf(sacc[nf][2])) | ((unsigned)f2bf(__expf(sacc[nf][3])) << 16);
      *(uint2*)&ES[(w * 16 + l15) * 72 + nf * 16 + lg * 4] = make_uint2(e0, e1);
    }
    const bf16x8 ea0 = *(const bf16x8*)&ES[(w * 16 + l15) * 72 + lg * 8];
    const bf16x8 ea1 = *(const bf16x8*)&ES[(w * 16 + l15) * 72 + 32 + lg * 8];
    pacc = __builtin_amdgcn_mfma_f32_16x16x32_bf16(ea0, ones, pacc, 0, 0, 0);
    pacc = __builtin_amdgcn_mfma_f32_16x16x32_bf16(ea1, ones, pacc, 0, 0, 0);
#pragma unroll
    for (int df = 0; df < 4; ++df) {
      const int d = df * 16 + l15;
      const int sw = 8 * ((d >> 2) & 7);
      const bf16x8 vb0 = *(const bf16x8*)&VT[d * 72 + ((lg * 8) ^ sw)];
      const bf16x8 vb1 = *(const bf16x8*)&VT[d * 72 + ((32 + lg * 8) ^ sw)];
      ctx[df] = __builtin_amdgcn_mfma_f32_16x16x32_bf16(ea0, vb0, ctx[df], 0, 0, 0);
      ctx[df] = __builtin_amdgcn_mfma_f32_16x16x32_bf16(ea1, vb1, ctx[df], 0, 0, 0);
    }
  }
  const size_t pbase = ((size_t)bh * 16 + chunk) * 4096;
#pragma unroll
  for (int df = 0; df < 4; ++df)
#pragma unroll
    for (int r = 0; r < 4; ++r)
      pctx[pbase + (w * 16 + lg * 4 + r) * 64 + df * 16 + l15] = ctx[df][r];
  if (l15 == 0) {
#pragma unroll
    for (int r = 0; r < 4; ++r)
      psum[((size_t)bh * 16 + chunk) * 64 + w * 16 + lg * 4 + r] = pacc[r];
  }
}

// K3: reduce partials -> context1 = ctxr @ Wv^T + bv, stored as bf16 (c1nbf).
// grid (bh, aq): 256 blocks. R11: pctx loads NONTEMPORAL (read-once, then dead).
__global__ __launch_bounds__(256) void k3_reduce(
    const float* __restrict__ pctx, const float* __restrict__ psum,
    const float* __restrict__ Wv, const float* __restrict__ bv,
    unsigned short* __restrict__ c1nbf) {
  const int bh = blockIdx.x, aq = blockIdx.y;
  const int tid = threadIdx.x;
  const int tn = tid & 15, tm = tid >> 4;
  __shared__ float sinv[16];
  __shared__ float CR[16][68];   // ctxr rows [a_local][d]
  __shared__ float WT[64][68];   // Wv^T [d][e]
  if (tid < 16) {
    const int a = aq * 16 + tid;
    float s = 0.f;
#pragma unroll 4
    for (int c = 0; c < 16; ++c) s += psum[((size_t)bh * 16 + c) * 64 + a];
    sinv[tid] = 1.0f / s;
  }
  for (int i = tid; i < 1024; i += 256) {
    const int e = i >> 4, d4 = (i & 15) * 4;
    const float4 f = *(const float4*)(Wv + e * 64 + d4);
    WT[d4 + 0][e] = f.x; WT[d4 + 1][e] = f.y;
    WT[d4 + 2][e] = f.z; WT[d4 + 3][e] = f.w;
  }
  __syncthreads();  // sinv + WT ready
  {
    const int al = tid >> 4, d4 = (tid & 15) * 4;
    const size_t base = (size_t)bh * 16 * 4096 + (size_t)(aq * 16 + al) * 64 + d4;
    float4 s = make_float4(0.f, 0.f, 0.f, 0.f);
#pragma unroll 4
    for (int c = 0; c < 16; ++c) {
      const f32x4 f = ntload4(pctx + base + (size_t)c * 4096);
      s.x += f.x; s.y += f.y; s.z += f.z; s.w += f.w;
    }
    const float si = sinv[al];
    CR[al][d4 + 0] = s.x * si; CR[al][d4 + 1] = s.y * si;
    CR[al][d4 + 2] = s.z * si; CR[al][d4 + 3] = s.w * si;
  }
  __syncthreads();
  float acc[4];
  const float4 bb = *(const float4*)(bv + tn * 4);
  acc[0] = bb.x; acc[1] = bb.y; acc[2] = bb.z; acc[3] = bb.w;
#pragma unroll 8
  for (int d = 0; d < 64; ++d) {
    const float a0 = CR[tm][d];  // broadcast within 16-lane group
    const float4 wv4 = *(const float4*)&WT[d][tn * 4];
    acc[0] = fmaf(a0, wv4.x, acc[0]);
    acc[1] = fmaf(a0, wv4.y, acc[1]);
    acc[2] = fmaf(a0, wv4.z, acc[2]);
    acc[3] = fmaf(a0, wv4.w, acc[3]);
  }
  ushort4 o;
  o.x = f2bf(acc[0]); o.y = f2bf(acc[1]); o.z = f2bf(acc[2]); o.w = f2bf(acc[3]);
  *(ushort4*)(c1nbf + (size_t)bh * 4096 + (size_t)(aq * 16 + tm) * 64 + tn * 4) = o;
}

// KG: GT[bh][e][a] = sum_d Wo[e][h*64+d] * c1n[bh][a][d], bf16.
__global__ __launch_bounds__(256) void kG(
    const unsigned short* __restrict__ c1nbf, const float* __restrict__ Wo,
    unsigned short* __restrict__ GT) {
  const int et = blockIdx.x;   // e-tile of 256
  const int bh = blockIdx.y, h = bh & 15;
  const int e0 = et * 256;
  __shared__ unsigned short WoS[256 * 72];  // [e][d]
  __shared__ unsigned short C1S[64 * 72];   // [a][d]
  const int tid = threadIdx.x;
  const int lane = tid & 63, w = tid >> 6;
  const int l15 = lane & 15, lg = lane >> 4;
  for (int i = tid; i < 4096; i += 256) {
    const int e = i >> 4, d4 = (i & 15) * 4;
    const float4 f = *(const float4*)(Wo + (size_t)(e0 + e) * DM + h * 64 + d4);
    ushort4 o;
    o.x = f2bf(f.x); o.y = f2bf(f.y); o.z = f2bf(f.z); o.w = f2bf(f.w);
    *(ushort4*)&WoS[e * 72 + d4] = o;
  }
  for (int i = tid; i < 512; i += 256) {
    const int a = i >> 3, d8 = (i & 7) * 8;
    *(uint4*)&C1S[a * 72 + d8] =
        *(const uint4*)(c1nbf + (size_t)bh * 4096 + a * 64 + d8);
  }
  __syncthreads();
  bf16x8 b0[4], b1[4];
#pragma unroll
  for (int at = 0; at < 4; ++at) {
    b0[at] = *(const bf16x8*)&C1S[(at * 16 + l15) * 72 + lg * 8];
    b1[at] = *(const bf16x8*)&C1S[(at * 16 + l15) * 72 + 32 + lg * 8];
  }
#pragma unroll
  for (int et16 = 0; et16 < 4; ++et16) {
    const int erow = w * 64 + et16 * 16 + l15;
    const bf16x8 a0 = *(const bf16x8*)&WoS[erow * 72 + lg * 8];
    const bf16x8 a1 = *(const bf16x8*)&WoS[erow * 72 + 32 + lg * 8];
#pragma unroll
    for (int at = 0; at < 4; ++at) {
      f32x4 acc = (f32x4){0.f, 0.f, 0.f, 0.f};
      acc = __builtin_amdgcn_mfma_f32_16x16x32_bf16(a0, b0[at], acc, 0, 0, 0);
      acc = __builtin_amdgcn_mfma_f32_16x16x32_bf16(a1, b1[at], acc, 0, 0, 0);
      const size_t gbase =
          ((size_t)bh * 1024 + e0 + w * 64 + et16 * 16 + lg * 4) * 64 + at * 16 + l15;
#pragma unroll
      for (int r = 0; r < 4; ++r) GT[gbase + (size_t)r * 64] = f2bf(acc[r]);
    }
  }
}

// K4: stage-2 QK + softmax only (PV folded into K5 via GT). grid(ntile, bh).
// Q A-frags loaded DIRECT from global (R11: NONTEMPORAL — 67 MB read-once;
// keep P2bf resident for k5). scores2 stores NONTEMPORAL (final output).
__global__ __launch_bounds__(256) void k4_mfma(
    const float* __restrict__ q, const unsigned short* __restrict__ c1nbf,
    float* __restrict__ scores2, unsigned short* __restrict__ P2bf) {
  __shared__ unsigned short C1N[64 * 72];  // c1n [a][d] bf16
  __shared__ unsigned short PS[64 * 72];   // P [n][a] bf16
  const int bh = blockIdx.y;
  const int n0 = blockIdx.x * 64;
  const int tid = threadIdx.x;
  const int lane = tid & 63, w = tid >> 6;
  const int l15 = lane & 15, lg = lane >> 4;

  for (int i = tid; i < 512; i += 256) {
    const int a = i >> 3, d8 = (i & 7) * 8;
    *(uint4*)&C1N[a * 72 + d8] =
        *(const uint4*)(c1nbf + (size_t)bh * 4096 + a * 64 + d8);
  }
  // direct A-frags: row = n0 + w*16 + l15, k-slices lg*8.. and 32+lg*8..
  const float* qr = q + ((size_t)bh * NN + n0 + w * 16 + l15) * HS;
  const f32x4 qa = ntload4(qr + lg * 8);
  const f32x4 qb = ntload4(qr + lg * 8 + 4);
  const f32x4 qc = ntload4(qr + 32 + lg * 8);
  const f32x4 qd = ntload4(qr + 32 + lg * 8 + 4);
  bf16x8 af0, af1;
  af0[0] = (short)f2bf(qa.x * SCALE); af0[1] = (short)f2bf(qa.y * SCALE);
  af0[2] = (short)f2bf(qa.z * SCALE); af0[3] = (short)f2bf(qa.w * SCALE);
  af0[4] = (short)f2bf(qb.x * SCALE); af0[5] = (short)f2bf(qb.y * SCALE);
  af0[6] = (short)f2bf(qb.z * SCALE); af0[7] = (short)f2bf(qb.w * SCALE);
  af1[0] = (short)f2bf(qc.x * SCALE); af1[1] = (short)f2bf(qc.y * SCALE);
  af1[2] = (short)f2bf(qc.z * SCALE); af1[3] = (short)f2bf(qc.w * SCALE);
  af1[4] = (short)f2bf(qd.x * SCALE); af1[5] = (short)f2bf(qd.y * SCALE);
  af1[6] = (short)f2bf(qd.z * SCALE); af1[7] = (short)f2bf(qd.w * SCALE);
  __syncthreads();  // C1N ready

  f32x4 sacc[4];
#pragma unroll
  for (int afr = 0; afr < 4; ++afr) {
    sacc[afr] = (f32x4){0.f, 0.f, 0.f, 0.f};
    const bf16x8 b0 = *(const bf16x8*)&C1N[(afr * 16 + l15) * 72 + lg * 8];
    const bf16x8 b1 = *(const bf16x8*)&C1N[(afr * 16 + l15) * 72 + 32 + lg * 8];
    sacc[afr] = __builtin_amdgcn_mfma_f32_16x16x32_bf16(af0, b0, sacc[afr], 0, 0, 0);
    sacc[afr] = __builtin_amdgcn_mfma_f32_16x16x32_bf16(af1, b1, sacc[afr], 0, 0, 0);
  }
  float p[4][4];  // [afr][r]
#pragma unroll
  for (int r = 0; r < 4; ++r) {
    float m = fmaxf(fmaxf(sacc[0][r], sacc[1][r]), fmaxf(sacc[2][r], sacc[3][r]));
#pragma unroll
    for (int off = 1; off < 16; off <<= 1) m = fmaxf(m, __shfl_xor(m, off));
    float s = 0.f;
#pragma unroll
    for (int afr = 0; afr < 4; ++afr) {
      p[afr][r] = __expf(sacc[afr][r] - m);
      s += p[afr][r];
    }
#pragma unroll
    for (int off = 1; off < 16; off <<= 1) s += __shfl_xor(s, off);
    const float inv = 1.0f / s;
    const size_t srow = ((size_t)bh * NN + n0 + w * 16 + lg * 4 + r) * NA;
#pragma unroll
    for (int afr = 0; afr < 4; ++afr) {
      p[afr][r] *= inv;
      __builtin_nontemporal_store(p[afr][r], &scores2[srow + afr * 16 + l15]);
      PS[(w * 16 + lg * 4 + r) * 72 + afr * 16 + l15] = f2bf(p[afr][r]);
    }
  }
  // copy wave-private PS rows -> P2bf (coalesced 128B per 4 lanes)
  const int prow = w * 16 + (lane >> 2);
  const int pch = (lane & 3) * 16;
  const uint4 v0 = *(const uint4*)&PS[prow * 72 + pch];
  const uint4 v1 = *(const uint4*)&PS[prow * 72 + pch + 8];
  unsigned short* gp = P2bf + ((size_t)bh * NN + n0 + prow) * NA + pch;
  *(uint4*)gp = v0;
  *(uint4*)(gp + 8) = v1;
}

// K5: out[b,n,:] = sum_h P2[b,h,n,:] @ GT[(b,h)] + bo.
// R6 occupancy-first design: tile 256x128, BK=64, single-buffered LDS
// (48KB -> 3 blocks/CU), 8 waves, wave tile 128x32, acc[8][2], gload_lds
// for BOTH operands. Grid dim3(64,8) x-major. out stores NONTEMPORAL.
__global__ __launch_bounds__(512, 4) void k5_mfma(
    const unsigned short* __restrict__ P2, const unsigned short* __restrict__ GT,
    const float* __restrict__ bo, float* __restrict__ out) {
  __shared__ unsigned short As[256 * 64];  // 32 KB
  __shared__ unsigned short Bs[128 * 64];  // 16 KB
  const int tid = threadIdx.x;
  const int lane = tid & 63;
  const int w = tid >> 6;             // 0..7
  const int wr = w >> 2, wc = w & 3;  // wave tile 128x32
  const int l15 = lane & 15, lg = lane >> 4;
  const int rp = blockIdx.x;          // row-panel 0..63
  const int e0 = blockIdx.y * 128;    // e-tile
  const int b16 = (rp >> 4) * 16;     // batch*16
  const int nloc0 = (rp & 15) * 256;

  const int srow8 = lane >> 3;                    // 0..7
  const int sslot = ((lane & 7) ^ srow8) << 4;    // pre-swizzled source slot

  f32x4 acc[8][2] = {{{0.f}}};

  for (int t = 0; t < 16; ++t) {
    const char* Ab = (const char*)(P2 + ((size_t)(b16 + t) * NN + nloc0) * NA);
    const char* Gb = (const char*)(GT + ((size_t)(b16 + t) * 1024 + e0) * NA);
#pragma unroll
    for (int j = 0; j < 4; ++j) {
      const int rb = j * 64 + w * 8;  // wave-uniform row base
      gload_lds16(Ab + (size_t)(rb + srow8) * 128 + sslot,
                  (char*)As + rb * 128 + lane * 16);
    }
#pragma unroll
    for (int j = 0; j < 2; ++j) {
      const int rb = j * 64 + w * 8;
      gload_lds16(Gb + (size_t)(rb + srow8) * 128 + sslot,
                  (char*)Bs + rb * 128 + lane * 16);
    }
    __syncthreads();  // compiler drains vmcnt -> As/Bs ready for all waves
#pragma unroll
    for (int ks = 0; ks < 2; ++ks) {
      bf16x8 af[8], bfr[2];
#pragma unroll
      for (int m = 0; m < 8; ++m) {
        const int r = wr * 128 + m * 16 + l15;
        const int byt = (ks * 64 + lg * 16) ^ ((r & 7) << 4);
        af[m] = *(const bf16x8*)((const char*)As + r * 128 + byt);
      }
#pragma unroll
      for (int n = 0; n < 2; ++n) {
        const int r = wc * 32 + n * 16 + l15;
        const int byt = (ks * 64 + lg * 16) ^ ((r & 7) << 4);
        bfr[n] = *(const bf16x8*)((const char*)Bs + r * 128 + byt);
      }
#pragma unroll
      for (int m = 0; m < 8; ++m)
#pragma unroll
        for (int n = 0; n < 2; ++n)
          acc[m][n] = __builtin_amdgcn_mfma_f32_16x16x32_bf16(af[m], bfr[n], acc[m][n], 0, 0, 0);
    }
    __syncthreads();  // all reads done before next stage overwrites
  }

  // epilogue: C row=(lane>>4)*4+reg, col=lane&15
  const size_t mrow0 = (size_t)(b16 >> 4) * NN + nloc0;
#pragma unroll
  for (int m = 0; m < 8; ++m) {
    const size_t row0 = mrow0 + wr * 128 + m * 16 + lg * 4;
#pragma unroll
    for (int n = 0; n < 2; ++n) {
      const int c = e0 + wc * 32 + n * 16 + l15;
      const float bias = bo[c];
#pragma unroll
      for (int r = 0; r < 4; ++r)
        __builtin_nontemporal_store(acc[m][n][r] + bias, &out[(row0 + r) * DM + c]);
    }
  }
}

extern "C" void kernel_launch(void* const* d_in, const int* in_sizes, int n_in,
                              void* d_out, int out_size, void* d_ws, size_t ws_size,
                              hipStream_t stream) {
  (void)in_sizes; (void)n_in; (void)out_size; (void)ws_size;
  const float* q  = (const float*)d_in[0];
  const float* k  = (const float*)d_in[1];
  const float* v  = (const float*)d_in[2];
  const float* Wq = (const float*)d_in[3];
  const float* bq = (const float*)d_in[4];
  const float* Wk = (const float*)d_in[5];
  const float* bk = (const float*)d_in[6];
  const float* Wv = (const float*)d_in[7];
  const float* bv = (const float*)d_in[8];
  const float* Wo = (const float*)d_in[9];
  const float* bo = (const float*)d_in[10];
  const float* ag = (const float*)d_in[11];
  (void)bk;  // constant-per-agent term cancels in softmax over n (exactly)

  float* out0 = (float*)d_out;                         // [B,N,D]
  float* scores2 = out0 + (size_t)NB * NN * DM;        // [B,H,N,A]

  float* ws = (float*)d_ws;
  unsigned short* foldqbf = (unsigned short*)ws;        // region: 65,536 f32
  unsigned short* c1nbf = (unsigned short*)(ws + 65536);  // region: 262,144 f32
  float* psum = ws + 65536 + 262144;                    // 65,536 f32
  float* pctx = psum + 65536;                           // 4,194,304 f32
  unsigned short* GT = (unsigned short*)pctx;           // alias (pctx dead after k3)
  unsigned short* P2bf = (unsigned short*)(pctx + 4194304);  // 16,777,216 bf16

  k0_fold<<<NH, 256, 0, stream>>>(ag, Wq, bq, Wk, foldqbf);
  k2_mfma<<<dim3(16, NBH), 256, 0, stream>>>(k, v, foldqbf, pctx, psum);
  k3_reduce<<<dim3(NBH, 4), 256, 0, stream>>>(pctx, psum, Wv, bv, c1nbf);
  kG<<<dim3(4, NBH), 256, 0, stream>>>(c1nbf, Wo, GT);
  k4_mfma<<<dim3(NN / 64, NBH), 256, 0, stream>>>(q, c1nbf, scores2, P2bf);
  k5_mfma<<<dim3(64, 8), 512, 0, stream>>>(P2bf, GT, bo, out0);
}

// Round 12
// 132.095 us; speedup vs baseline: 1.0636x; 1.0636x over previous
//
#include <hip/hip_runtime.h>

#define NB 4
#define NH 16
#define NN 4096
#define HS 64
#define NA 64
#define DM 1024
#define NBH (NB*NH)
#define SCALE 0.125f

typedef __attribute__((ext_vector_type(8))) short bf16x8;
typedef __attribute__((ext_vector_type(4))) float f32x4;

__device__ __forceinline__ unsigned short f2bf(float f) {
  unsigned u = __float_as_uint(f);
  u += 0x7FFF + ((u >> 16) & 1);  // RNE
  return (unsigned short)(u >> 16);
}

__device__ __forceinline__ void gload_lds16(const void* g, void* l) {
  __builtin_amdgcn_global_load_lds(
      (const __attribute__((address_space(1))) unsigned int*)g,
      (__attribute__((address_space(3))) unsigned int*)l, 16, 0, 0);
}

__device__ __forceinline__ void dot44(float (&c)[4][4], const float4 (&a)[4], const float4 (&b)[4]) {
#pragma unroll
  for (int i = 0; i < 4; ++i)
#pragma unroll
    for (int j = 0; j < 4; ++j) {
      c[i][j] = fmaf(a[i].x, b[j].x, c[i][j]);
      c[i][j] = fmaf(a[i].y, b[j].y, c[i][j]);
      c[i][j] = fmaf(a[i].z, b[j].z, c[i][j]);
      c[i][j] = fmaf(a[i].w, b[j].w, c[i][j]);
    }
}

// K0: foldq[h][a][d] = ((agents[h]@Wq^T + bq) @ Wk) * SCALE, as bf16.
__global__ __launch_bounds__(256) void k0_fold(
    const float* __restrict__ agents, const float* __restrict__ Wq,
    const float* __restrict__ bq, const float* __restrict__ Wk,
    unsigned short* __restrict__ foldqbf) {
  const int h = blockIdx.x, tid = threadIdx.x;
  const int tn = tid & 15, tm = tid >> 4;
  __shared__ float AG[64][68];   // agents [a][d]
  __shared__ float WB[64][68];   // Wq [e][d]
  __shared__ float QA[64][68];   // q_agents [a][e]
  __shared__ float WKT[64][68];  // Wk^T [d][e]
  for (int i = tid; i < 1024; i += 256) {
    const int r = i >> 4, c4 = (i & 15) * 4;
    *(float4*)&AG[r][c4] = *(const float4*)(agents + h * 4096 + r * 64 + c4);
    *(float4*)&WB[r][c4] = *(const float4*)(Wq + r * 64 + c4);
    const float4 f = *(const float4*)(Wk + r * 64 + c4);  // Wk[e=r][d4..]
    WKT[c4 + 0][r] = f.x; WKT[c4 + 1][r] = f.y;
    WKT[c4 + 2][r] = f.z; WKT[c4 + 3][r] = f.w;
  }
  __syncthreads();
  {
    const float4 bb = *(const float4*)(bq + tn * 4);
    float acc[4][4];
#pragma unroll
    for (int i = 0; i < 4; ++i) {
      acc[i][0] = bb.x; acc[i][1] = bb.y; acc[i][2] = bb.z; acc[i][3] = bb.w;
    }
    for (int d4 = 0; d4 < 64; d4 += 4) {
      float4 a4[4], b4[4];
#pragma unroll
      for (int i = 0; i < 4; ++i) a4[i] = *(const float4*)&AG[tm * 4 + i][d4];
#pragma unroll
      for (int j = 0; j < 4; ++j) b4[j] = *(const float4*)&WB[tn * 4 + j][d4];
      dot44(acc, a4, b4);
    }
#pragma unroll
    for (int i = 0; i < 4; ++i)
      *(float4*)&QA[tm * 4 + i][tn * 4] =
          make_float4(acc[i][0], acc[i][1], acc[i][2], acc[i][3]);
  }
  __syncthreads();
  {
    float acc[4][4] = {};
    for (int e4 = 0; e4 < 64; e4 += 4) {
      float4 a4[4], b4[4];
#pragma unroll
      for (int i = 0; i < 4; ++i) a4[i] = *(const float4*)&QA[tm * 4 + i][e4];
#pragma unroll
      for (int j = 0; j < 4; ++j) b4[j] = *(const float4*)&WKT[tn * 4 + j][e4];
      dot44(acc, a4, b4);
    }
#pragma unroll
    for (int i = 0; i < 4; ++i) {
      ushort4 o;
      o.x = f2bf(acc[i][0] * SCALE); o.y = f2bf(acc[i][1] * SCALE);
      o.z = f2bf(acc[i][2] * SCALE); o.w = f2bf(acc[i][3] * SCALE);
      *(ushort4*)(foldqbf + h * 4096 + (tm * 4 + i) * 64 + tn * 4) = o;
    }
  }
}

// K2: stage-1 flash partials via bf16 MFMA. grid(chunk=16, bh=64), 4 waves.
// R7: a-partitioned QK (swapped operands) -> ES wave-private, 2 barriers/tile.
// Plain loads (R11 lesson: NT loads bypass L2 on gfx950 and cost ~7 us).
__global__ __launch_bounds__(256) void k2_mfma(
    const float* __restrict__ kraw, const float* __restrict__ vraw,
    const unsigned short* __restrict__ foldqbf,
    float* __restrict__ pctx, float* __restrict__ psum) {
  __shared__ unsigned short FQ[64 * 72];  // foldq [a][d], scaled bf16
  __shared__ unsigned short KN[64 * 72];  // K natural [n][d]
  __shared__ unsigned short VT[64 * 72];  // V^T [d][n ^ 8*((d>>2)&7)]
  __shared__ unsigned short ES[64 * 72];  // exp scores [a][n], wave-private rows
  const int chunk = blockIdx.x, bh = blockIdx.y, h = bh & 15;
  const int tid = threadIdx.x;
  const int lane = tid & 63, w = tid >> 6;
  const int l15 = lane & 15, lg = lane >> 4;

  const size_t kvbase = ((size_t)bh * NN + chunk * 256) * HS;
  float4 kreg[4], vreg[4];
#pragma unroll
  for (int i0 = 0; i0 < 4; ++i0) {
    const int i = tid + i0 * 256;
    kreg[i0] = *(const float4*)(kraw + kvbase + (size_t)i * 4);
    vreg[i0] = *(const float4*)(vraw + kvbase + (size_t)i * 4);
  }

  for (int i = tid; i < 512; i += 256) {
    const int a = i >> 3, d8 = (i & 7) * 8;
    *(uint4*)&FQ[a * 72 + d8] = *(const uint4*)(foldqbf + h * 4096 + a * 64 + d8);
  }

  f32x4 ctx[4];
#pragma unroll
  for (int df = 0; df < 4; ++df) ctx[df] = (f32x4){0.f, 0.f, 0.f, 0.f};
  f32x4 pacc = (f32x4){0.f, 0.f, 0.f, 0.f};
  const short one_bf = (short)0x3F80;
  const bf16x8 ones = {one_bf, one_bf, one_bf, one_bf, one_bf, one_bf, one_bf, one_bf};

  for (int t = 0; t < 4; ++t) {
    __syncthreads();  // bar A: prev PV reads of KN/VT done
#pragma unroll
    for (int i0 = 0; i0 < 4; ++i0) {
      const int i = tid + i0 * 256;
      const int n = i >> 4, d4 = (i & 15) * 4;
      const float4 f = kreg[i0];
      const unsigned klo = f2bf(f.x) | ((unsigned)f2bf(f.y) << 16);
      const unsigned khi = f2bf(f.z) | ((unsigned)f2bf(f.w) << 16);
      *(uint2*)&KN[n * 72 + d4] = make_uint2(klo, khi);
      const float4 g = vreg[i0];
      const int nn = n ^ (8 * (i & 7));
      VT[(d4 + 0) * 72 + nn] = f2bf(g.x);
      VT[(d4 + 1) * 72 + nn] = f2bf(g.y);
      VT[(d4 + 2) * 72 + nn] = f2bf(g.z);
      VT[(d4 + 3) * 72 + nn] = f2bf(g.w);
    }
    if (t < 3) {
#pragma unroll
      for (int i0 = 0; i0 < 4; ++i0) {
        const int i = tid + i0 * 256;
        kreg[i0] = *(const float4*)(kraw + kvbase + (size_t)(t + 1) * 4096 + (size_t)i * 4);
        vreg[i0] = *(const float4*)(vraw + kvbase + (size_t)(t + 1) * 4096 + (size_t)i * 4);
      }
    }
    __syncthreads();  // bar B: KN/VT (and FQ) ready
    // ---- QK, a-partitioned: wave w owns a-cols w*16..w*16+15 ----
    const bf16x8 bq0 = *(const bf16x8*)&FQ[(w * 16 + l15) * 72 + lg * 8];
    const bf16x8 bq1 = *(const bf16x8*)&FQ[(w * 16 + l15) * 72 + 32 + lg * 8];
    f32x4 sacc[4];
#pragma unroll
    for (int nf = 0; nf < 4; ++nf) {
      sacc[nf] = (f32x4){0.f, 0.f, 0.f, 0.f};
      const bf16x8 a0 = *(const bf16x8*)&KN[(nf * 16 + l15) * 72 + lg * 8];
      const bf16x8 a1 = *(const bf16x8*)&KN[(nf * 16 + l15) * 72 + 32 + lg * 8];
      sacc[nf] = __builtin_amdgcn_mfma_f32_16x16x32_bf16(a0, bq0, sacc[nf], 0, 0, 0);
      sacc[nf] = __builtin_amdgcn_mfma_f32_16x16x32_bf16(a1, bq1, sacc[nf], 0, 0, 0);
    }
#pragma unroll
    for (int nf = 0; nf < 4; ++nf) {
      const unsigned e0 = f2bf(__expf(sacc[nf][0])) | ((unsigned)f2bf(__expf(sacc[nf][1])) << 16);
      const unsigned e1 = f2bf(__expf(sacc[nf][2])) | ((unsigned)f2bf(__expf(sacc[nf][3])) << 16);
      *(uint2*)&ES[(w * 16 + l15) * 72 + nf * 16 + lg * 4] = make_uint2(e0, e1);
    }
    const bf16x8 ea0 = *(const bf16x8*)&ES[(w * 16 + l15) * 72 + lg * 8];
    const bf16x8 ea1 = *(const bf16x8*)&ES[(w * 16 + l15) * 72 + 32 + lg * 8];
    pacc = __builtin_amdgcn_mfma_f32_16x16x32_bf16(ea0, ones, pacc, 0, 0, 0);
    pacc = __builtin_amdgcn_mfma_f32_16x16x32_bf16(ea1, ones, pacc, 0, 0, 0);
#pragma unroll
    for (int df = 0; df < 4; ++df) {
      const int d = df * 16 + l15;
      const int sw = 8 * ((d >> 2) & 7);
      const bf16x8 vb0 = *(const bf16x8*)&VT[d * 72 + ((lg * 8) ^ sw)];
      const bf16x8 vb1 = *(const bf16x8*)&VT[d * 72 + ((32 + lg * 8) ^ sw)];
      ctx[df] = __builtin_amdgcn_mfma_f32_16x16x32_bf16(ea0, vb0, ctx[df], 0, 0, 0);
      ctx[df] = __builtin_amdgcn_mfma_f32_16x16x32_bf16(ea1, vb1, ctx[df], 0, 0, 0);
    }
  }
  const size_t pbase = ((size_t)bh * 16 + chunk) * 4096;
#pragma unroll
  for (int df = 0; df < 4; ++df)
#pragma unroll
    for (int r = 0; r < 4; ++r)
      pctx[pbase + (w * 16 + lg * 4 + r) * 64 + df * 16 + l15] = ctx[df][r];
  if (l15 == 0) {
#pragma unroll
    for (int r = 0; r < 4; ++r)
      psum[((size_t)bh * 16 + chunk) * 64 + w * 16 + lg * 4 + r] = pacc[r];
  }
}

// K3: reduce partials -> context1 = ctxr @ Wv^T + bv, stored as bf16 (c1nbf).
// grid (bh, aq): 256 blocks; each block handles 16 agent rows.
__global__ __launch_bounds__(256) void k3_reduce(
    const float* __restrict__ pctx, const float* __restrict__ psum,
    const float* __restrict__ Wv, const float* __restrict__ bv,
    unsigned short* __restrict__ c1nbf) {
  const int bh = blockIdx.x, aq = blockIdx.y;
  const int tid = threadIdx.x;
  const int tn = tid & 15, tm = tid >> 4;
  __shared__ float sinv[16];
  __shared__ float CR[16][68];   // ctxr rows [a_local][d]
  __shared__ float WT[64][68];   // Wv^T [d][e]
  if (tid < 16) {
    const int a = aq * 16 + tid;
    float s = 0.f;
#pragma unroll 4
    for (int c = 0; c < 16; ++c) s += psum[((size_t)bh * 16 + c) * 64 + a];
    sinv[tid] = 1.0f / s;
  }
  for (int i = tid; i < 1024; i += 256) {
    const int e = i >> 4, d4 = (i & 15) * 4;
    const float4 f = *(const float4*)(Wv + e * 64 + d4);
    WT[d4 + 0][e] = f.x; WT[d4 + 1][e] = f.y;
    WT[d4 + 2][e] = f.z; WT[d4 + 3][e] = f.w;
  }
  __syncthreads();  // sinv + WT ready
  {
    const int al = tid >> 4, d4 = (tid & 15) * 4;
    const size_t base = (size_t)bh * 16 * 4096 + (size_t)(aq * 16 + al) * 64 + d4;
    float4 s = make_float4(0.f, 0.f, 0.f, 0.f);
#pragma unroll 4
    for (int c = 0; c < 16; ++c) {
      const float4 f = *(const float4*)(pctx + base + (size_t)c * 4096);
      s.x += f.x; s.y += f.y; s.z += f.z; s.w += f.w;
    }
    const float si = sinv[al];
    CR[al][d4 + 0] = s.x * si; CR[al][d4 + 1] = s.y * si;
    CR[al][d4 + 2] = s.z * si; CR[al][d4 + 3] = s.w * si;
  }
  __syncthreads();
  float acc[4];
  const float4 bb = *(const float4*)(bv + tn * 4);
  acc[0] = bb.x; acc[1] = bb.y; acc[2] = bb.z; acc[3] = bb.w;
#pragma unroll 8
  for (int d = 0; d < 64; ++d) {
    const float a0 = CR[tm][d];  // broadcast within 16-lane group
    const float4 wv4 = *(const float4*)&WT[d][tn * 4];
    acc[0] = fmaf(a0, wv4.x, acc[0]);
    acc[1] = fmaf(a0, wv4.y, acc[1]);
    acc[2] = fmaf(a0, wv4.z, acc[2]);
    acc[3] = fmaf(a0, wv4.w, acc[3]);
  }
  ushort4 o;
  o.x = f2bf(acc[0]); o.y = f2bf(acc[1]); o.z = f2bf(acc[2]); o.w = f2bf(acc[3]);
  *(ushort4*)(c1nbf + (size_t)bh * 4096 + (size_t)(aq * 16 + tm) * 64 + tn * 4) = o;
}

// KG: GT[bh][e][a] = sum_d Wo[e][h*64+d] * c1n[bh][a][d], bf16.
__global__ __launch_bounds__(256) void kG(
    const unsigned short* __restrict__ c1nbf, const float* __restrict__ Wo,
    unsigned short* __restrict__ GT) {
  const int et = blockIdx.x;   // e-tile of 256
  const int bh = blockIdx.y, h = bh & 15;
  const int e0 = et * 256;
  __shared__ unsigned short WoS[256 * 72];  // [e][d]
  __shared__ unsigned short C1S[64 * 72];   // [a][d]
  const int tid = threadIdx.x;
  const int lane = tid & 63, w = tid >> 6;
  const int l15 = lane & 15, lg = lane >> 4;
  for (int i = tid; i < 4096; i += 256) {
    const int e = i >> 4, d4 = (i & 15) * 4;
    const float4 f = *(const float4*)(Wo + (size_t)(e0 + e) * DM + h * 64 + d4);
    ushort4 o;
    o.x = f2bf(f.x); o.y = f2bf(f.y); o.z = f2bf(f.z); o.w = f2bf(f.w);
    *(ushort4*)&WoS[e * 72 + d4] = o;
  }
  for (int i = tid; i < 512; i += 256) {
    const int a = i >> 3, d8 = (i & 7) * 8;
    *(uint4*)&C1S[a * 72 + d8] =
        *(const uint4*)(c1nbf + (size_t)bh * 4096 + a * 64 + d8);
  }
  __syncthreads();
  bf16x8 b0[4], b1[4];
#pragma unroll
  for (int at = 0; at < 4; ++at) {
    b0[at] = *(const bf16x8*)&C1S[(at * 16 + l15) * 72 + lg * 8];
    b1[at] = *(const bf16x8*)&C1S[(at * 16 + l15) * 72 + 32 + lg * 8];
  }
#pragma unroll
  for (int et16 = 0; et16 < 4; ++et16) {
    const int erow = w * 64 + et16 * 16 + l15;
    const bf16x8 a0 = *(const bf16x8*)&WoS[erow * 72 + lg * 8];
    const bf16x8 a1 = *(const bf16x8*)&WoS[erow * 72 + 32 + lg * 8];
#pragma unroll
    for (int at = 0; at < 4; ++at) {
      f32x4 acc = (f32x4){0.f, 0.f, 0.f, 0.f};
      acc = __builtin_amdgcn_mfma_f32_16x16x32_bf16(a0, b0[at], acc, 0, 0, 0);
      acc = __builtin_amdgcn_mfma_f32_16x16x32_bf16(a1, b1[at], acc, 0, 0, 0);
      const size_t gbase =
          ((size_t)bh * 1024 + e0 + w * 64 + et16 * 16 + lg * 4) * 64 + at * 16 + l15;
#pragma unroll
      for (int r = 0; r < 4; ++r) GT[gbase + (size_t)r * 64] = f2bf(acc[r]);
    }
  }
}

// K4: stage-2 QK + softmax only (PV folded into K5 via GT). grid(ntile, bh).
// Q A-frags loaded DIRECT from global into registers (plain loads); no QN
// LDS. scores2 stores NONTEMPORAL (final output, never re-read on device).
__global__ __launch_bounds__(256) void k4_mfma(
    const float* __restrict__ q, const unsigned short* __restrict__ c1nbf,
    float* __restrict__ scores2, unsigned short* __restrict__ P2bf) {
  __shared__ unsigned short C1N[64 * 72];  // c1n [a][d] bf16
  __shared__ unsigned short PS[64 * 72];   // P [n][a] bf16
  const int bh = blockIdx.y;
  const int n0 = blockIdx.x * 64;
  const int tid = threadIdx.x;
  const int lane = tid & 63, w = tid >> 6;
  const int l15 = lane & 15, lg = lane >> 4;

  for (int i = tid; i < 512; i += 256) {
    const int a = i >> 3, d8 = (i & 7) * 8;
    *(uint4*)&C1N[a * 72 + d8] =
        *(const uint4*)(c1nbf + (size_t)bh * 4096 + a * 64 + d8);
  }
  // direct A-frags: row = n0 + w*16 + l15, k-slices lg*8.. and 32+lg*8..
  const float* qr = q + ((size_t)bh * NN + n0 + w * 16 + l15) * HS;
  const float4 qa = *(const float4*)(qr + lg * 8);
  const float4 qb = *(const float4*)(qr + lg * 8 + 4);
  const float4 qc = *(const float4*)(qr + 32 + lg * 8);
  const float4 qd = *(const float4*)(qr + 32 + lg * 8 + 4);
  bf16x8 af0, af1;
  af0[0] = (short)f2bf(qa.x * SCALE); af0[1] = (short)f2bf(qa.y * SCALE);
  af0[2] = (short)f2bf(qa.z * SCALE); af0[3] = (short)f2bf(qa.w * SCALE);
  af0[4] = (short)f2bf(qb.x * SCALE); af0[5] = (short)f2bf(qb.y * SCALE);
  af0[6] = (short)f2bf(qb.z * SCALE); af0[7] = (short)f2bf(qb.w * SCALE);
  af1[0] = (short)f2bf(qc.x * SCALE); af1[1] = (short)f2bf(qc.y * SCALE);
  af1[2] = (short)f2bf(qc.z * SCALE); af1[3] = (short)f2bf(qc.w * SCALE);
  af1[4] = (short)f2bf(qd.x * SCALE); af1[5] = (short)f2bf(qd.y * SCALE);
  af1[6] = (short)f2bf(qd.z * SCALE); af1[7] = (short)f2bf(qd.w * SCALE);
  __syncthreads();  // C1N ready

  f32x4 sacc[4];
#pragma unroll
  for (int afr = 0; afr < 4; ++afr) {
    sacc[afr] = (f32x4){0.f, 0.f, 0.f, 0.f};
    const bf16x8 b0 = *(const bf16x8*)&C1N[(afr * 16 + l15) * 72 + lg * 8];
    const bf16x8 b1 = *(const bf16x8*)&C1N[(afr * 16 + l15) * 72 + 32 + lg * 8];
    sacc[afr] = __builtin_amdgcn_mfma_f32_16x16x32_bf16(af0, b0, sacc[afr], 0, 0, 0);
    sacc[afr] = __builtin_amdgcn_mfma_f32_16x16x32_bf16(af1, b1, sacc[afr], 0, 0, 0);
  }
  float p[4][4];  // [afr][r]
#pragma unroll
  for (int r = 0; r < 4; ++r) {
    float m = fmaxf(fmaxf(sacc[0][r], sacc[1][r]), fmaxf(sacc[2][r], sacc[3][r]));
#pragma unroll
    for (int off = 1; off < 16; off <<= 1) m = fmaxf(m, __shfl_xor(m, off));
    float s = 0.f;
#pragma unroll
    for (int afr = 0; afr < 4; ++afr) {
      p[afr][r] = __expf(sacc[afr][r] - m);
      s += p[afr][r];
    }
#pragma unroll
    for (int off = 1; off < 16; off <<= 1) s += __shfl_xor(s, off);
    const float inv = 1.0f / s;
    const size_t srow = ((size_t)bh * NN + n0 + w * 16 + lg * 4 + r) * NA;
#pragma unroll
    for (int afr = 0; afr < 4; ++afr) {
      p[afr][r] *= inv;
      __builtin_nontemporal_store(p[afr][r], &scores2[srow + afr * 16 + l15]);
      PS[(w * 16 + lg * 4 + r) * 72 + afr * 16 + l15] = f2bf(p[afr][r]);
    }
  }
  // copy wave-private PS rows -> P2bf (coalesced 128B per 4 lanes)
  const int prow = w * 16 + (lane >> 2);
  const int pch = (lane & 3) * 16;
  const uint4 v0 = *(const uint4*)&PS[prow * 72 + pch];
  const uint4 v1 = *(const uint4*)&PS[prow * 72 + pch + 8];
  unsigned short* gp = P2bf + ((size_t)bh * NN + n0 + prow) * NA + pch;
  *(uint4*)gp = v0;
  *(uint4*)(gp + 8) = v1;
}

// K5: out[b,n,:] = sum_h P2[b,h,n,:] @ GT[(b,h)] + bo.
// R6 occupancy-first design (best measured): tile 256x128, BK=64,
// single-buffered LDS (48KB -> 3 blocks/CU), 8 waves, wave tile 128x32,
// acc[8][2], gload_lds for BOTH operands. Grid dim3(64,8) x-major:
// all 8 e-tiles of a row-panel share an XCD. out stores NONTEMPORAL
// (final output, never re-read -> keep GT/P2bf resident in L2/L3).
__global__ __launch_bounds__(512, 4) void k5_mfma(
    const unsigned short* __restrict__ P2, const unsigned short* __restrict__ GT,
    const float* __restrict__ bo, float* __restrict__ out) {
  __shared__ unsigned short As[256 * 64];  // 32 KB
  __shared__ unsigned short Bs[128 * 64];  // 16 KB
  const int tid = threadIdx.x;
  const int lane = tid & 63;
  const int w = tid >> 6;             // 0..7
  const int wr = w >> 2, wc = w & 3;  // wave tile 128x32
  const int l15 = lane & 15, lg = lane >> 4;
  const int rp = blockIdx.x;          // row-panel 0..63
  const int e0 = blockIdx.y * 128;    // e-tile
  const int b16 = (rp >> 4) * 16;     // batch*16
  const int nloc0 = (rp & 15) * 256;

  const int srow8 = lane >> 3;                    // 0..7
  const int sslot = ((lane & 7) ^ srow8) << 4;    // pre-swizzled source slot

  f32x4 acc[8][2] = {{{0.f}}};

  for (int t = 0; t < 16; ++t) {
    const char* Ab = (const char*)(P2 + ((size_t)(b16 + t) * NN + nloc0) * NA);
    const char* Gb = (const char*)(GT + ((size_t)(b16 + t) * 1024 + e0) * NA);
#pragma unroll
    for (int j = 0; j < 4; ++j) {
      const int rb = j * 64 + w * 8;  // wave-uniform row base
      gload_lds16(Ab + (size_t)(rb + srow8) * 128 + sslot,
                  (char*)As + rb * 128 + lane * 16);
    }
#pragma unroll
    for (int j = 0; j < 2; ++j) {
      const int rb = j * 64 + w * 8;
      gload_lds16(Gb + (size_t)(rb + srow8) * 128 + sslot,
                  (char*)Bs + rb * 128 + lane * 16);
    }
    __syncthreads();  // compiler drains vmcnt -> As/Bs ready for all waves
#pragma unroll
    for (int ks = 0; ks < 2; ++ks) {
      bf16x8 af[8], bfr[2];
#pragma unroll
      for (int m = 0; m < 8; ++m) {
        const int r = wr * 128 + m * 16 + l15;
        const int byt = (ks * 64 + lg * 16) ^ ((r & 7) << 4);
        af[m] = *(const bf16x8*)((const char*)As + r * 128 + byt);
      }
#pragma unroll
      for (int n = 0; n < 2; ++n) {
        const int r = wc * 32 + n * 16 + l15;
        const int byt = (ks * 64 + lg * 16) ^ ((r & 7) << 4);
        bfr[n] = *(const bf16x8*)((const char*)Bs + r * 128 + byt);
      }
#pragma unroll
      for (int m = 0; m < 8; ++m)
#pragma unroll
        for (int n = 0; n < 2; ++n)
          acc[m][n] = __builtin_amdgcn_mfma_f32_16x16x32_bf16(af[m], bfr[n], acc[m][n], 0, 0, 0);
    }
    __syncthreads();  // all reads done before next stage overwrites
  }

  // epilogue: C row=(lane>>4)*4+reg, col=lane&15
  const size_t mrow0 = (size_t)(b16 >> 4) * NN + nloc0;
#pragma unroll
  for (int m = 0; m < 8; ++m) {
    const size_t row0 = mrow0 + wr * 128 + m * 16 + lg * 4;
#pragma unroll
    for (int n = 0; n < 2; ++n) {
      const int c = e0 + wc * 32 + n * 16 + l15;
      const float bias = bo[c];
#pragma unroll
      for (int r = 0; r < 4; ++r)
        __builtin_nontemporal_store(acc[m][n][r] + bias, &out[(row0 + r) * DM + c]);
    }
  }
}

extern "C" void kernel_launch(void* const* d_in, const int* in_sizes, int n_in,
                              void* d_out, int out_size, void* d_ws, size_t ws_size,
                              hipStream_t stream) {
  (void)in_sizes; (void)n_in; (void)out_size; (void)ws_size;
  const float* q  = (const float*)d_in[0];
  const float* k  = (const float*)d_in[1];
  const float* v  = (const float*)d_in[2];
  const float* Wq = (const float*)d_in[3];
  const float* bq = (const float*)d_in[4];
  const float* Wk = (const float*)d_in[5];
  const float* bk = (const float*)d_in[6];
  const float* Wv = (const float*)d_in[7];
  const float* bv = (const float*)d_in[8];
  const float* Wo = (const float*)d_in[9];
  const float* bo = (const float*)d_in[10];
  const float* ag = (const float*)d_in[11];
  (void)bk;  // constant-per-agent term cancels in softmax over n (exactly)

  float* out0 = (float*)d_out;                         // [B,N,D]
  float* scores2 = out0 + (size_t)NB * NN * DM;        // [B,H,N,A]

  float* ws = (float*)d_ws;
  unsigned short* foldqbf = (unsigned short*)ws;        // region: 65,536 f32
  unsigned short* c1nbf = (unsigned short*)(ws + 65536);  // region: 262,144 f32
  float* psum = ws + 65536 + 262144;                    // 65,536 f32
  float* pctx = psum + 65536;                           // 4,194,304 f32
  unsigned short* GT = (unsigned short*)pctx;           // alias (pctx dead after k3)
  unsigned short* P2bf = (unsigned short*)(pctx + 4194304);  // 16,777,216 bf16

  k0_fold<<<NH, 256, 0, stream>>>(ag, Wq, bq, Wk, foldqbf);
  k2_mfma<<<dim3(16, NBH), 256, 0, stream>>>(k, v, foldqbf, pctx, psum);
  k3_reduce<<<dim3(NBH, 4), 256, 0, stream>>>(pctx, psum, Wv, bv, c1nbf);
  kG<<<dim3(4, NBH), 256, 0, stream>>>(c1nbf, Wo, GT);
  k4_mfma<<<dim3(NN / 64, NBH), 256, 0, stream>>>(q, c1nbf, scores2, P2bf);
  k5_mfma<<<dim3(64, 8), 512, 0, stream>>>(P2bf, GT, bo, out0);
}